// Round 1
// 1084.939 us; speedup vs baseline: 1.0225x; 1.0225x over previous
//
#include <hip/hip_runtime.h>
#include <stdint.h>

// MoE: T=8192 tokens, D=1024, E=8 experts, H=4096, top-2. fp32 IO, bf16 MFMA internal.
#define T_TOK 8192
#define D_DIM 1024
#define E_NUM 8
#define H_DIM 4096

#define BM 128
#define BN 128
#define BK 64
#define NSEG 8                           // expert segments (slots merged: a token never repeats an expert)
#define MAX_ROWS2 17408                  // >= 2*T + 8*127, multiple of BM
#define MAX_MT2 (MAX_ROWS2/BM)           // 136
#define KSPLIT 2                         // fc2 K-split for tail-quantization

typedef unsigned short u16;
typedef __attribute__((ext_vector_type(8))) short shortx8;
typedef __attribute__((ext_vector_type(4))) float floatx4;
typedef __attribute__((ext_vector_type(8))) unsigned short ushortx8;

typedef const __attribute__((address_space(1))) unsigned int g_uint;
typedef __attribute__((address_space(3))) unsigned int l_uint;

__device__ __forceinline__ u16 f2bf(float f) {
  union { float f; unsigned int u; } v; v.f = f;
  unsigned int r = v.u + 0x7FFFu + ((v.u >> 16) & 1u);  // RTNE
  return (u16)(r >> 16);
}
__device__ __forceinline__ void gld_lds16(const u16* g, u16* l) {
  __builtin_amdgcn_global_load_lds((g_uint*)g, (l_uint*)l, 16, 0, 0);
}
// tanh-approx GELU via sigmoid: gelu(v) ~= v * sigmoid(1.5957691216 v + 0.07135481627 v^3)
// max abs err ~5e-4; bf16 storage noise dominates. ~9 VALU ops vs ~30 for erff.
__device__ __forceinline__ float gelu_fast(float v) {
  float y = v * (1.5957691216f + 0.07135481627f * v * v);
  y = fminf(y, 30.f);                      // overflow guard (inputs bounded ~|v|<5 anyway)
  float ey = __expf(y);
  return v * ey * __builtin_amdgcn_rcpf(1.f + ey);
}

// ---------------- init ------------------------------------------------------
__global__ __launch_bounds__(256) void init_kernel(int* counts, int* fills, int* row_token) {
  int i = blockIdx.x * 256 + threadIdx.x;
  if (i < MAX_ROWS2) row_token[i] = -1;
  if (blockIdx.x == 0 && threadIdx.x < NSEG) { counts[threadIdx.x] = 0; fills[threadIdx.x] = 0; }
}

// ---------------- zero out (float4) -----------------------------------------
__global__ __launch_bounds__(256) void zero4_kernel(float4* out) {
  out[(size_t)blockIdx.x * 256 + threadIdx.x] = float4{0.f, 0.f, 0.f, 0.f};
}

// ---------------- convert x fp32 -> bf16 ------------------------------------
__global__ __launch_bounds__(256) void convert_x_kernel(const float* __restrict__ X, u16* __restrict__ XC) {
  size_t i = ((size_t)blockIdx.x * 256 + threadIdx.x) * 8;
  float4 a = *(const float4*)&X[i];
  float4 b = *(const float4*)&X[i + 4];
  ushortx8 o;
  o[0] = f2bf(a.x); o[1] = f2bf(a.y); o[2] = f2bf(a.z); o[3] = f2bf(a.w);
  o[4] = f2bf(b.x); o[5] = f2bf(b.y); o[6] = f2bf(b.z); o[7] = f2bf(b.w);
  *(ushortx8*)&XC[i] = o;
}

// ---------------- gating: one wave per token, all fp32 ----------------------
__global__ __launch_bounds__(256) void gate_kernel(const float* __restrict__ X, const float* __restrict__ GW,
                                                   int* __restrict__ tk_idx, float* __restrict__ tk_w,
                                                   int* __restrict__ counts) {
  const int lane = threadIdx.x & 63;
  const int t = blockIdx.x * 4 + (threadIdx.x >> 6);
  const float4* xr4 = (const float4*)(X + (size_t)t * D_DIM + lane * 16);
  const float4* gw4 = (const float4*)GW;
  float acc[E_NUM];
#pragma unroll
  for (int e = 0; e < E_NUM; e++) acc[e] = 0.f;
#pragma unroll
  for (int i4 = 0; i4 < 4; i4++) {
    float4 xv = xr4[i4];
#pragma unroll
    for (int c = 0; c < 4; c++) {
      float xs = (&xv.x)[c];
      int d = lane * 16 + i4 * 4 + c;
      float4 g0 = gw4[d * 2], g1 = gw4[d * 2 + 1];
      acc[0] += xs * g0.x; acc[1] += xs * g0.y; acc[2] += xs * g0.z; acc[3] += xs * g0.w;
      acc[4] += xs * g1.x; acc[5] += xs * g1.y; acc[6] += xs * g1.z; acc[7] += xs * g1.w;
    }
  }
#pragma unroll
  for (int e = 0; e < E_NUM; e++)
    for (int off = 32; off; off >>= 1) acc[e] += __shfl_xor(acc[e], off);
  if (lane == 0) {
    int i0 = 0; float v0 = acc[0];
#pragma unroll
    for (int e = 1; e < E_NUM; e++) if (acc[e] > v0) { v0 = acc[e]; i0 = e; }
    int i1 = -1; float v1 = -1e30f;
#pragma unroll
    for (int e = 0; e < E_NUM; e++) if (e != i0 && acc[e] > v1) { v1 = acc[e]; i1 = e; }
    float e1 = expf(v1 - v0);           // v1 <= v0, stable
    float inv = 1.f / (1.f + e1);
    tk_idx[t * 2] = i0; tk_idx[t * 2 + 1] = i1;
    tk_w[t * 2] = inv;  tk_w[t * 2 + 1] = e1 * inv;
    atomicAdd(&counts[i0], 1); atomicAdd(&counts[i1], 1);
  }
}

// ---------------- prefix over 8 expert segments, padded to BM ---------------
__global__ void prefix_kernel(const int* counts, int* seg) {
  if (threadIdx.x == 0 && blockIdx.x == 0) {
    int a = 0;
    for (int i = 0; i < NSEG; i++) { seg[i] = a; a += ((counts[i] + BM - 1) / BM) * BM; }
    seg[NSEG] = a;
  }
}

// ---------------- fill: scatter tokens into packed rows ---------------------
__global__ __launch_bounds__(256) void fill_kernel(const int* __restrict__ tk_idx, const float* __restrict__ tk_w,
                                                   const int* __restrict__ seg, int* __restrict__ fills,
                                                   int* __restrict__ row_token, float* __restrict__ row_weight) {
  int t = blockIdx.x * 256 + threadIdx.x;
  if (t >= T_TOK) return;
#pragma unroll
  for (int s = 0; s < 2; s++) {
    int sidx = tk_idx[t * 2 + s];
    int pos = atomicAdd(&fills[sidx], 1);
    int r = seg[sidx] + pos;
    row_token[r] = t; row_weight[r] = tk_w[t * 2 + s];
  }
}

// -------- weight convert+transpose fp32 [R][C] -> bf16 [C][R] ---------------
__global__ __launch_bounds__(256) void transpose_kernel(const float* __restrict__ src, u16* __restrict__ dst,
                                                        int R, int C) {
  __shared__ u16 tile[32][33];
  int tx = threadIdx.x & 31, ty = threadIdx.x >> 5;   // ty 0..7
  size_t off = (size_t)blockIdx.z * R * C;
  int r0 = blockIdx.y * 32, c0 = blockIdx.x * 32;
#pragma unroll
  for (int i = 0; i < 32; i += 8) tile[ty + i][tx] = f2bf(src[off + (size_t)(r0 + ty + i) * C + c0 + tx]);
  __syncthreads();
#pragma unroll
  for (int i = 0; i < 32; i += 8) dst[off + (size_t)(c0 + ty + i) * R + r0 + tx] = tile[tx][ty + i];
}

// ---------------- fc1: Hbuf(bf16) = gelu(Xc @ W1t[e] + b1) ------------------
__global__ __launch_bounds__(256, 3) void fc1_kernel(const u16* __restrict__ XC, const u16* __restrict__ W1T,
                                                     const float* __restrict__ B1, u16* __restrict__ Hbuf,
                                                     const int* __restrict__ row_token, const int* __restrict__ seg,
                                                     int mtile0, int e_filter) {
  const int mtile = mtile0 + blockIdx.y, ntile = blockIdx.x;
  const int row0 = mtile * BM;
  if (row0 >= seg[NSEG]) return;
  int sidx = 0;
#pragma unroll
  for (int i = 1; i < NSEG; i++) if (row0 >= seg[i]) sidx = i;
  const int e = sidx;
  if (e_filter >= 0 && e != e_filter) return;
  const size_t ebase = (e_filter >= 0) ? 0 : (size_t)e * H_DIM;
  const u16* Bbase = W1T + (ebase + (size_t)ntile * BN) * D_DIM;

  __shared__ u16 lA[BM * BK];
  __shared__ u16 lB[BN * BK];
  const int tid = threadIdx.x;
  const u16* gA[4]; const u16* gB[4];
#pragma unroll
  for (int r = 0; r < 4; r++) {
    int c = r * 256 + tid;
    int arow = c >> 3, acol = (c & 7) * 8;
    int tok = row_token[row0 + arow]; if (tok < 0) tok = 0;   // pad rows: dummy token, discarded
    gA[r] = XC + (size_t)tok * D_DIM + acol;
    gB[r] = Bbase + (size_t)arow * D_DIM + acol;
  }
  const int lane = tid & 63;
  const int mq = (tid >> 7) & 1, nq = (tid >> 6) & 1;
  const int lrow = lane & 15, quad = lane >> 4;
  floatx4 acc[4][4];
#pragma unroll
  for (int i = 0; i < 4; i++)
#pragma unroll
    for (int j = 0; j < 4; j++)
#pragma unroll
      for (int r = 0; r < 4; r++) acc[i][j][r] = 0.f;

  for (int k0 = 0; k0 < D_DIM; k0 += BK) {
#pragma unroll
    for (int r = 0; r < 4; r++) gld_lds16(gA[r] + k0, &lA[(r * 256 + tid) * 8]);
#pragma unroll
    for (int r = 0; r < 4; r++) gld_lds16(gB[r] + k0, &lB[(r * 256 + tid) * 8]);
    __syncthreads();
#pragma unroll
    for (int kk = 0; kk < 2; kk++) {
      shortx8 af[4], bfr[4];
#pragma unroll
      for (int i = 0; i < 4; i++) af[i]  = *(const shortx8*)&lA[(mq * 64 + i * 16 + lrow) * BK + kk * 32 + quad * 8];
#pragma unroll
      for (int i = 0; i < 4; i++) bfr[i] = *(const shortx8*)&lB[(nq * 64 + i * 16 + lrow) * BK + kk * 32 + quad * 8];
#pragma unroll
      for (int i = 0; i < 4; i++)
#pragma unroll
        for (int j = 0; j < 4; j++)
          acc[i][j] = __builtin_amdgcn_mfma_f32_16x16x32_bf16(af[i], bfr[j], acc[i][j], 0, 0, 0);
    }
    __syncthreads();
  }
#pragma unroll
  for (int j = 0; j < 4; j++) {
    float bv = B1[(size_t)e * H_DIM + ntile * BN + nq * 64 + j * 16 + lrow];
#pragma unroll
    for (int i = 0; i < 4; i++)
#pragma unroll
      for (int rr = 0; rr < 4; rr++) {
        int hrow = (mtile - mtile0) * BM + mq * 64 + i * 16 + quad * 4 + rr;
        float v = acc[i][j][rr] + bv;
        Hbuf[(size_t)hrow * H_DIM + (size_t)ntile * BN + nq * 64 + j * 16 + lrow] = f2bf(gelu_fast(v));
      }
  }
}

// ---------------- fc2: out += atomics (single pass, K-split) ----------------
__global__ __launch_bounds__(256, 3) void fc2_kernel(const u16* __restrict__ Hbuf, const u16* __restrict__ W2T,
                                                     const float* __restrict__ B2, float* __restrict__ out,
                                                     const int* __restrict__ row_token, const float* __restrict__ row_weight,
                                                     const int* __restrict__ seg,
                                                     int mtile0, int e_filter) {
  const int mtile = mtile0 + blockIdx.y, ntile = blockIdx.x;
  const int kz = blockIdx.z;
  const int row0 = mtile * BM;
  if (row0 >= seg[NSEG]) return;
  int sidx = 0;
#pragma unroll
  for (int i = 1; i < NSEG; i++) if (row0 >= seg[i]) sidx = i;
  const int e = sidx;
  if (e_filter >= 0 && e != e_filter) return;
  const size_t ebase = (e_filter >= 0) ? 0 : (size_t)e * D_DIM;
  const u16* Bbase = W2T + (ebase + (size_t)ntile * BN) * H_DIM;

  __shared__ u16 lA[BM * BK];
  __shared__ u16 lB[BN * BK];
  const int tid = threadIdx.x;
  const u16* gA[4]; const u16* gB[4];
#pragma unroll
  for (int r = 0; r < 4; r++) {
    int c = r * 256 + tid;
    int arow = c >> 3, acol = (c & 7) * 8;
    gA[r] = Hbuf + (size_t)((mtile - mtile0) * BM + arow) * H_DIM + acol;
    gB[r] = Bbase + (size_t)arow * H_DIM + acol;
  }
  const int lane = tid & 63;
  const int mq = (tid >> 7) & 1, nq = (tid >> 6) & 1;
  const int lrow = lane & 15, quad = lane >> 4;
  floatx4 acc[4][4];
#pragma unroll
  for (int i = 0; i < 4; i++)
#pragma unroll
    for (int j = 0; j < 4; j++)
#pragma unroll
      for (int r = 0; r < 4; r++) acc[i][j][r] = 0.f;

  const int kbeg = kz * (H_DIM / KSPLIT);
  const int kend = kbeg + (H_DIM / KSPLIT);
  for (int k0 = kbeg; k0 < kend; k0 += BK) {
#pragma unroll
    for (int r = 0; r < 4; r++) gld_lds16(gA[r] + k0, &lA[(r * 256 + tid) * 8]);
#pragma unroll
    for (int r = 0; r < 4; r++) gld_lds16(gB[r] + k0, &lB[(r * 256 + tid) * 8]);
    __syncthreads();
#pragma unroll
    for (int kk = 0; kk < 2; kk++) {
      shortx8 af[4], bfr[4];
#pragma unroll
      for (int i = 0; i < 4; i++) af[i]  = *(const shortx8*)&lA[(mq * 64 + i * 16 + lrow) * BK + kk * 32 + quad * 8];
#pragma unroll
      for (int i = 0; i < 4; i++) bfr[i] = *(const shortx8*)&lB[(nq * 64 + i * 16 + lrow) * BK + kk * 32 + quad * 8];
#pragma unroll
      for (int i = 0; i < 4; i++)
#pragma unroll
        for (int j = 0; j < 4; j++)
          acc[i][j] = __builtin_amdgcn_mfma_f32_16x16x32_bf16(af[i], bfr[j], acc[i][j], 0, 0, 0);
    }
    __syncthreads();
  }
  // epilogue: (+b2 only from kz==0), scale by gate weight, atomic accumulate
#pragma unroll
  for (int i = 0; i < 4; i++)
#pragma unroll
    for (int rr = 0; rr < 4; rr++) {
      int gr = row0 + mq * 64 + i * 16 + quad * 4 + rr;
      int tok = row_token[gr];
      if (tok >= 0) {
        float wgt = row_weight[gr];
        size_t base = (size_t)tok * D_DIM + (size_t)ntile * BN + nq * 64 + lrow;
#pragma unroll
        for (int j = 0; j < 4; j++) {
          float bv = (kz == 0) ? B2[(size_t)e * D_DIM + ntile * BN + nq * 64 + j * 16 + lrow] : 0.f;
          float val = (acc[i][j][rr] + bv) * wgt;
          unsafeAtomicAdd(&out[base + j * 16], val);
        }
      }
    }
}

extern "C" void kernel_launch(void* const* d_in, const int* in_sizes, int n_in,
                              void* d_out, int out_size, void* d_ws, size_t ws_size,
                              hipStream_t stream) {
  const float* x  = (const float*)d_in[0];   // [T][D] fp32
  const float* gw = (const float*)d_in[1];   // [D][E]
  const float* w1 = (const float*)d_in[2];   // [E][D][H]
  const float* b1 = (const float*)d_in[3];   // [E][H]
  const float* w2 = (const float*)d_in[4];   // [E][H][D]
  const float* b2 = (const float*)d_in[5];   // [E][D]
  float* out = (float*)d_out;

  char* p = (char*)d_ws;
  auto alloc = [&](size_t n) { char* q = p; p += (n + 255) & ~(size_t)255; return q; };
  int*   counts     = (int*)alloc(NSEG * 4);
  int*   fills      = (int*)alloc(NSEG * 4);
  int*   seg        = (int*)alloc((NSEG + 1) * 4);
  int*   tk_idx     = (int*)alloc((size_t)T_TOK * 2 * 4);
  float* tk_w       = (float*)alloc((size_t)T_TOK * 2 * 4);
  int*   row_token  = (int*)alloc((size_t)MAX_ROWS2 * 4);
  float* row_weight = (float*)alloc((size_t)MAX_ROWS2 * 4);
  u16*   xc         = (u16*)alloc((size_t)T_TOK * D_DIM * 2);   // 16.8 MB bf16 x
  size_t meta = (size_t)(p - (char*)d_ws);

  const size_t Wfull = (size_t)E_NUM * H_DIM * D_DIM * 2;   // 67.1 MB bf16
  const size_t Wone  = (size_t)H_DIM * D_DIM * 2;           //  8.4 MB bf16
  auto hbytes = [](int n) { int cmx = (MAX_MT2 + n - 1) / n; return (size_t)cmx * BM * H_DIM * 2; };

  // mode 0: separate W1T+W2T, transposes hoisted; mode 1: shared W, transposes per chunk;
  // mode 2: per-expert W; mode 3: ws too small.
  int mode = 3, N = 1;
  {
    const int cand[6] = {1, 2, 4, 8, 16, 32};
    for (int ci = 0; ci < 6 && mode == 3; ci++)
      if (meta + 2 * Wfull + hbytes(cand[ci]) <= ws_size) { mode = 0; N = cand[ci]; }
    for (int ci = 0; ci < 6 && mode == 3; ci++)
      if (meta + Wfull + hbytes(cand[ci]) <= ws_size) { mode = 1; N = cand[ci]; }
    for (int ci = 0; ci < 6 && mode == 3; ci++)
      if (meta + Wone + hbytes(cand[ci]) <= ws_size) { mode = 2; N = cand[ci]; }
  }

  if (mode == 3) {  // ws too small for any tier: defined output, diagnostic fail
    zero4_kernel<<<(int)(((size_t)T_TOK * D_DIM) / 1024), 256, 0, stream>>>((float4*)out);
    return;
  }

  u16 *W1T, *W2T;
  if (mode == 0) { W1T = (u16*)alloc(Wfull); W2T = (u16*)alloc(Wfull); }
  else           { W1T = W2T = (u16*)alloc(mode == 1 ? Wfull : Wone); }
  u16* Hbuf = (u16*)alloc(hbytes(N));
  const int cm = (MAX_MT2 + N - 1) / N;

  init_kernel<<<(MAX_ROWS2 + 255) / 256, 256, 0, stream>>>(counts, fills, row_token);
  convert_x_kernel<<<(int)(((size_t)T_TOK * D_DIM) / 2048), 256, 0, stream>>>(x, xc);
  gate_kernel<<<T_TOK / 4, 256, 0, stream>>>(x, gw, tk_idx, tk_w, counts);
  prefix_kernel<<<1, 64, 0, stream>>>(counts, seg);
  fill_kernel<<<T_TOK / 256, 256, 0, stream>>>(tk_idx, tk_w, seg, fills, row_token, row_weight);
  zero4_kernel<<<(int)(((size_t)T_TOK * D_DIM) / 1024), 256, 0, stream>>>((float4*)out);

  if (mode == 0) {
    transpose_kernel<<<dim3(H_DIM / 32, D_DIM / 32, E_NUM), 256, 0, stream>>>(w1, W1T, D_DIM, H_DIM);
    transpose_kernel<<<dim3(D_DIM / 32, H_DIM / 32, E_NUM), 256, 0, stream>>>(w2, W2T, H_DIM, D_DIM);
  }

  for (int c = 0; c < N; ++c) {
    int mtile0 = c * cm;
    int cmc = MAX_MT2 - mtile0; if (cmc > cm) cmc = cm; if (cmc <= 0) break;
    if (mode == 0) {
      fc1_kernel<<<dim3(H_DIM / BN, cmc), 256, 0, stream>>>(xc, W1T, b1, Hbuf, row_token, seg, mtile0, -1);
      fc2_kernel<<<dim3(D_DIM / BN, cmc, KSPLIT), 256, 0, stream>>>(Hbuf, W2T, b2, out, row_token, row_weight, seg, mtile0, -1);
    } else if (mode == 1) {
      transpose_kernel<<<dim3(H_DIM / 32, D_DIM / 32, E_NUM), 256, 0, stream>>>(w1, W1T, D_DIM, H_DIM);
      fc1_kernel<<<dim3(H_DIM / BN, cmc), 256, 0, stream>>>(xc, W1T, b1, Hbuf, row_token, seg, mtile0, -1);
      transpose_kernel<<<dim3(D_DIM / 32, H_DIM / 32, E_NUM), 256, 0, stream>>>(w2, W2T, H_DIM, D_DIM);
      fc2_kernel<<<dim3(D_DIM / BN, cmc, KSPLIT), 256, 0, stream>>>(Hbuf, W2T, b2, out, row_token, row_weight, seg, mtile0, -1);
    } else {
      for (int e = 0; e < E_NUM; e++) {
        transpose_kernel<<<dim3(H_DIM / 32, D_DIM / 32, 1), 256, 0, stream>>>(w1 + (size_t)e * D_DIM * H_DIM, W1T, D_DIM, H_DIM);
        fc1_kernel<<<dim3(H_DIM / BN, cmc), 256, 0, stream>>>(xc, W1T, b1, Hbuf, row_token, seg, mtile0, e);
      }
      for (int e = 0; e < E_NUM; e++) {
        transpose_kernel<<<dim3(D_DIM / 32, H_DIM / 32, 1), 256, 0, stream>>>(w2 + (size_t)e * H_DIM * D_DIM, W2T, H_DIM, D_DIM);
        fc2_kernel<<<dim3(D_DIM / BN, cmc, KSPLIT), 256, 0, stream>>>(Hbuf, W2T, b2, out, row_token, row_weight, seg, mtile0, e);
      }
    }
  }
}

// Round 2
// 1025.289 us; speedup vs baseline: 1.0820x; 1.0582x over previous
//
#include <hip/hip_runtime.h>
#include <stdint.h>

// MoE: T=8192 tokens, D=1024, E=8 experts, H=4096, top-2. fp32 IO, bf16 MFMA internal.
#define T_TOK 8192
#define D_DIM 1024
#define E_NUM 8
#define H_DIM 4096

#define BM 128
#define BN 128
#define BK 64
#define NSEG 8                           // expert segments (a token never repeats an expert)
#define MAX_ROWS2 17408                  // >= 2*T + 8*127, multiple of BM
#define MAX_MT2 (MAX_ROWS2/BM)           // 136

typedef unsigned short u16;
typedef __attribute__((ext_vector_type(8))) short shortx8;
typedef __attribute__((ext_vector_type(4))) float floatx4;
typedef __attribute__((ext_vector_type(8))) unsigned short ushortx8;

typedef const __attribute__((address_space(1))) unsigned int g_uint;
typedef __attribute__((address_space(3))) unsigned int l_uint;

__device__ __forceinline__ u16 f2bf(float f) {
  union { float f; unsigned int u; } v; v.f = f;
  unsigned int r = v.u + 0x7FFFu + ((v.u >> 16) & 1u);  // RTNE
  return (u16)(r >> 16);
}
__device__ __forceinline__ void gld_lds16(const u16* g, u16* l) {
  __builtin_amdgcn_global_load_lds((g_uint*)g, (l_uint*)l, 16, 0, 0);
}
// tanh-approx GELU via sigmoid: gelu(v) ~= v * sigmoid(1.5957691216 v + 0.07135481627 v^3)
__device__ __forceinline__ float gelu_fast(float v) {
  float y = v * (1.5957691216f + 0.07135481627f * v * v);
  y = fminf(y, 30.f);                      // overflow guard
  float ey = __expf(y);
  return v * ey * __builtin_amdgcn_rcpf(1.f + ey);
}

// ---------------- init ------------------------------------------------------
__global__ __launch_bounds__(256) void init_kernel(int* counts, int* fills, int* row_token) {
  int i = blockIdx.x * 256 + threadIdx.x;
  if (i < MAX_ROWS2) row_token[i] = -1;
  if (blockIdx.x == 0 && threadIdx.x < NSEG) { counts[threadIdx.x] = 0; fills[threadIdx.x] = 0; }
}

// ---------------- zero out (float4), fallback only --------------------------
__global__ __launch_bounds__(256) void zero4_kernel(float4* out) {
  out[(size_t)blockIdx.x * 256 + threadIdx.x] = float4{0.f, 0.f, 0.f, 0.f};
}

// ---------------- convert x fp32 -> bf16 ------------------------------------
__global__ __launch_bounds__(256) void convert_x_kernel(const float* __restrict__ X, u16* __restrict__ XC) {
  size_t i = ((size_t)blockIdx.x * 256 + threadIdx.x) * 8;
  float4 a = *(const float4*)&X[i];
  float4 b = *(const float4*)&X[i + 4];
  ushortx8 o;
  o[0] = f2bf(a.x); o[1] = f2bf(a.y); o[2] = f2bf(a.z); o[3] = f2bf(a.w);
  o[4] = f2bf(b.x); o[5] = f2bf(b.y); o[6] = f2bf(b.z); o[7] = f2bf(b.w);
  *(ushortx8*)&XC[i] = o;
}

// ---------------- gating: one wave per token, all fp32 ----------------------
__global__ __launch_bounds__(256) void gate_kernel(const float* __restrict__ X, const float* __restrict__ GW,
                                                   int* __restrict__ tk_idx, float* __restrict__ tk_w,
                                                   int* __restrict__ counts) {
  const int lane = threadIdx.x & 63;
  const int t = blockIdx.x * 4 + (threadIdx.x >> 6);
  const float4* xr4 = (const float4*)(X + (size_t)t * D_DIM + lane * 16);
  const float4* gw4 = (const float4*)GW;
  float acc[E_NUM];
#pragma unroll
  for (int e = 0; e < E_NUM; e++) acc[e] = 0.f;
#pragma unroll
  for (int i4 = 0; i4 < 4; i4++) {
    float4 xv = xr4[i4];
#pragma unroll
    for (int c = 0; c < 4; c++) {
      float xs = (&xv.x)[c];
      int d = lane * 16 + i4 * 4 + c;
      float4 g0 = gw4[d * 2], g1 = gw4[d * 2 + 1];
      acc[0] += xs * g0.x; acc[1] += xs * g0.y; acc[2] += xs * g0.z; acc[3] += xs * g0.w;
      acc[4] += xs * g1.x; acc[5] += xs * g1.y; acc[6] += xs * g1.z; acc[7] += xs * g1.w;
    }
  }
#pragma unroll
  for (int e = 0; e < E_NUM; e++)
    for (int off = 32; off; off >>= 1) acc[e] += __shfl_xor(acc[e], off);
  if (lane == 0) {
    int i0 = 0; float v0 = acc[0];
#pragma unroll
    for (int e = 1; e < E_NUM; e++) if (acc[e] > v0) { v0 = acc[e]; i0 = e; }
    int i1 = -1; float v1 = -1e30f;
#pragma unroll
    for (int e = 0; e < E_NUM; e++) if (e != i0 && acc[e] > v1) { v1 = acc[e]; i1 = e; }
    float e1 = expf(v1 - v0);           // v1 <= v0, stable
    float inv = 1.f / (1.f + e1);
    tk_idx[t * 2] = i0; tk_idx[t * 2 + 1] = i1;
    tk_w[t * 2] = inv;  tk_w[t * 2 + 1] = e1 * inv;
    atomicAdd(&counts[i0], 1); atomicAdd(&counts[i1], 1);
  }
}

// ---------------- prefix over 8 expert segments, padded to BM ---------------
__global__ void prefix_kernel(const int* counts, int* seg) {
  if (threadIdx.x == 0 && blockIdx.x == 0) {
    int a = 0;
    for (int i = 0; i < NSEG; i++) { seg[i] = a; a += ((counts[i] + BM - 1) / BM) * BM; }
    seg[NSEG] = a;
  }
}

// ---------------- fill: scatter tokens into packed rows ---------------------
__global__ __launch_bounds__(256) void fill_kernel(const int* __restrict__ tk_idx, const float* __restrict__ tk_w,
                                                   const int* __restrict__ seg, int* __restrict__ fills,
                                                   int* __restrict__ row_token, float* __restrict__ row_weight,
                                                   int* __restrict__ row_of) {
  int t = blockIdx.x * 256 + threadIdx.x;
  if (t >= T_TOK) return;
#pragma unroll
  for (int s = 0; s < 2; s++) {
    int sidx = tk_idx[t * 2 + s];
    int pos = atomicAdd(&fills[sidx], 1);
    int r = seg[sidx] + pos;
    row_token[r] = t; row_weight[r] = tk_w[t * 2 + s];
    row_of[t * 2 + s] = r;
  }
}

// -------- weight convert+transpose fp32 [R][C] -> bf16 [C][R], 64x64 tiles --
// read: float4 coalesced; write: ushortx8 (16B) coalesced via LDS bounce.
__global__ __launch_bounds__(256) void transpose_kernel(const float* __restrict__ src, u16* __restrict__ dst,
                                                        int R, int C) {
  __shared__ u16 tile[64][68];            // row stride 136B (8B-aligned, odd dword -> spread banks)
  const int tid = threadIdx.x;
  size_t off = (size_t)blockIdx.z * (size_t)R * C;
  int r0 = blockIdx.y * 64, c0 = blockIdx.x * 64;
  int rr = tid >> 4, cc = (tid & 15) * 4;
#pragma unroll
  for (int i = 0; i < 4; i++) {
    int r = rr + i * 16;
    float4 v = *(const float4*)&src[off + (size_t)(r0 + r) * C + c0 + cc];
    u16* tp = &tile[r][cc];
    tp[0] = f2bf(v.x); tp[1] = f2bf(v.y); tp[2] = f2bf(v.z); tp[3] = f2bf(v.w);
  }
  __syncthreads();
  int c = tid >> 3, rb = (tid & 7) * 8;
#pragma unroll
  for (int i = 0; i < 2; i++) {
    int cx = c + i * 32;
    ushortx8 o;
#pragma unroll
    for (int q = 0; q < 8; q++) o[q] = tile[rb + q][cx];
    *(ushortx8*)&dst[off + (size_t)(c0 + cx) * R + r0 + rb] = o;
  }
}

// ---------------- fc1: Hbuf(bf16) = gelu(Xc @ W1t[e] + b1) ------------------
__global__ __launch_bounds__(256, 3) void fc1_kernel(const u16* __restrict__ XC, const u16* __restrict__ W1T,
                                                     const float* __restrict__ B1, u16* __restrict__ Hbuf,
                                                     const int* __restrict__ row_token, const int* __restrict__ seg,
                                                     int mtile0, int e_filter) {
  const int mtile = mtile0 + blockIdx.y, ntile = blockIdx.x;
  const int row0 = mtile * BM;
  if (row0 >= seg[NSEG]) return;
  int sidx = 0;
#pragma unroll
  for (int i = 1; i < NSEG; i++) if (row0 >= seg[i]) sidx = i;
  const int e = sidx;
  if (e_filter >= 0 && e != e_filter) return;
  const size_t ebase = (e_filter >= 0) ? 0 : (size_t)e * H_DIM;
  const u16* Bbase = W1T + (ebase + (size_t)ntile * BN) * D_DIM;

  __shared__ u16 lA[BM * BK];
  __shared__ u16 lB[BN * BK];
  const int tid = threadIdx.x;
  const u16* gA[4]; const u16* gB[4];
#pragma unroll
  for (int r = 0; r < 4; r++) {
    int c = r * 256 + tid;
    int arow = c >> 3, acol = (c & 7) * 8;
    int tok = row_token[row0 + arow]; if (tok < 0) tok = 0;   // pad rows: dummy token, discarded
    gA[r] = XC + (size_t)tok * D_DIM + acol;
    gB[r] = Bbase + (size_t)arow * D_DIM + acol;
  }
  const int lane = tid & 63;
  const int mq = (tid >> 7) & 1, nq = (tid >> 6) & 1;
  const int lrow = lane & 15, quad = lane >> 4;
  floatx4 acc[4][4];
#pragma unroll
  for (int i = 0; i < 4; i++)
#pragma unroll
    for (int j = 0; j < 4; j++)
#pragma unroll
      for (int r = 0; r < 4; r++) acc[i][j][r] = 0.f;

  for (int k0 = 0; k0 < D_DIM; k0 += BK) {
#pragma unroll
    for (int r = 0; r < 4; r++) gld_lds16(gA[r] + k0, &lA[(r * 256 + tid) * 8]);
#pragma unroll
    for (int r = 0; r < 4; r++) gld_lds16(gB[r] + k0, &lB[(r * 256 + tid) * 8]);
    __syncthreads();
#pragma unroll
    for (int kk = 0; kk < 2; kk++) {
      shortx8 af[4], bfr[4];
#pragma unroll
      for (int i = 0; i < 4; i++) af[i]  = *(const shortx8*)&lA[(mq * 64 + i * 16 + lrow) * BK + kk * 32 + quad * 8];
#pragma unroll
      for (int i = 0; i < 4; i++) bfr[i] = *(const shortx8*)&lB[(nq * 64 + i * 16 + lrow) * BK + kk * 32 + quad * 8];
#pragma unroll
      for (int i = 0; i < 4; i++)
#pragma unroll
        for (int j = 0; j < 4; j++)
          acc[i][j] = __builtin_amdgcn_mfma_f32_16x16x32_bf16(af[i], bfr[j], acc[i][j], 0, 0, 0);
    }
    __syncthreads();
  }
#pragma unroll
  for (int j = 0; j < 4; j++) {
    float bv = B1[(size_t)e * H_DIM + ntile * BN + nq * 64 + j * 16 + lrow];
#pragma unroll
    for (int i = 0; i < 4; i++)
#pragma unroll
      for (int rr = 0; rr < 4; rr++) {
        int hrow = (mtile - mtile0) * BM + mq * 64 + i * 16 + quad * 4 + rr;
        float v = acc[i][j][rr] + bv;
        Hbuf[(size_t)hrow * H_DIM + (size_t)ntile * BN + nq * 64 + j * 16 + lrow] = f2bf(gelu_fast(v));
      }
  }
}

// ---------------- fc2: outbuf[row][D] = (Hbuf @ W2t[e] + b2) * wgt ----------
__global__ __launch_bounds__(256, 3) void fc2_kernel(const u16* __restrict__ Hbuf, const u16* __restrict__ W2T,
                                                     const float* __restrict__ B2, float* __restrict__ outbuf,
                                                     const int* __restrict__ row_token, const float* __restrict__ row_weight,
                                                     const int* __restrict__ seg,
                                                     int mtile0, int e_filter) {
  const int mtile = mtile0 + blockIdx.y, ntile = blockIdx.x;
  const int row0 = mtile * BM;
  if (row0 >= seg[NSEG]) return;
  int sidx = 0;
#pragma unroll
  for (int i = 1; i < NSEG; i++) if (row0 >= seg[i]) sidx = i;
  const int e = sidx;
  if (e_filter >= 0 && e != e_filter) return;
  const size_t ebase = (e_filter >= 0) ? 0 : (size_t)e * D_DIM;
  const u16* Bbase = W2T + (ebase + (size_t)ntile * BN) * H_DIM;

  __shared__ u16 lA[BM * BK];
  __shared__ u16 lB[BN * BK];
  const int tid = threadIdx.x;
  const u16* gA[4]; const u16* gB[4];
#pragma unroll
  for (int r = 0; r < 4; r++) {
    int c = r * 256 + tid;
    int arow = c >> 3, acol = (c & 7) * 8;
    gA[r] = Hbuf + (size_t)((mtile - mtile0) * BM + arow) * H_DIM + acol;
    gB[r] = Bbase + (size_t)arow * H_DIM + acol;
  }
  const int lane = tid & 63;
  const int mq = (tid >> 7) & 1, nq = (tid >> 6) & 1;
  const int lrow = lane & 15, quad = lane >> 4;
  floatx4 acc[4][4];
#pragma unroll
  for (int i = 0; i < 4; i++)
#pragma unroll
    for (int j = 0; j < 4; j++)
#pragma unroll
      for (int r = 0; r < 4; r++) acc[i][j][r] = 0.f;

  for (int k0 = 0; k0 < H_DIM; k0 += BK) {
#pragma unroll
    for (int r = 0; r < 4; r++) gld_lds16(gA[r] + k0, &lA[(r * 256 + tid) * 8]);
#pragma unroll
    for (int r = 0; r < 4; r++) gld_lds16(gB[r] + k0, &lB[(r * 256 + tid) * 8]);
    __syncthreads();
#pragma unroll
    for (int kk = 0; kk < 2; kk++) {
      shortx8 af[4], bfr[4];
#pragma unroll
      for (int i = 0; i < 4; i++) af[i]  = *(const shortx8*)&lA[(mq * 64 + i * 16 + lrow) * BK + kk * 32 + quad * 8];
#pragma unroll
      for (int i = 0; i < 4; i++) bfr[i] = *(const shortx8*)&lB[(nq * 64 + i * 16 + lrow) * BK + kk * 32 + quad * 8];
#pragma unroll
      for (int i = 0; i < 4; i++)
#pragma unroll
        for (int j = 0; j < 4; j++)
          acc[i][j] = __builtin_amdgcn_mfma_f32_16x16x32_bf16(af[i], bfr[j], acc[i][j], 0, 0, 0);
    }
    __syncthreads();
  }
  // epilogue: +b2, scale by gate weight, single plain store per element
#pragma unroll
  for (int i = 0; i < 4; i++)
#pragma unroll
    for (int rr = 0; rr < 4; rr++) {
      int gr = row0 + mq * 64 + i * 16 + quad * 4 + rr;
      int tok = row_token[gr];
      if (tok >= 0) {
        float wgt = row_weight[gr];
        float* obase = outbuf + (size_t)gr * D_DIM + (size_t)ntile * BN + nq * 64 + lrow;
#pragma unroll
        for (int j = 0; j < 4; j++) {
          float bv = B2[(size_t)e * D_DIM + ntile * BN + nq * 64 + j * 16 + lrow];
          obase[j * 16] = (acc[i][j][rr] + bv) * wgt;
        }
      }
    }
}

// ---------------- combine: out[t] = outbuf[r0] + outbuf[r1] -----------------
__global__ __launch_bounds__(256) void combine_kernel(const float* __restrict__ outbuf, const int* __restrict__ row_of,
                                                      float* __restrict__ out) {
  int t = blockIdx.x;
  int d = threadIdx.x * 4;
  int r0 = row_of[t * 2], r1 = row_of[t * 2 + 1];
  float4 a = *(const float4*)&outbuf[(size_t)r0 * D_DIM + d];
  float4 b = *(const float4*)&outbuf[(size_t)r1 * D_DIM + d];
  *(float4*)&out[(size_t)t * D_DIM + d] = float4{a.x + b.x, a.y + b.y, a.z + b.z, a.w + b.w};
}

extern "C" void kernel_launch(void* const* d_in, const int* in_sizes, int n_in,
                              void* d_out, int out_size, void* d_ws, size_t ws_size,
                              hipStream_t stream) {
  const float* x  = (const float*)d_in[0];   // [T][D] fp32
  const float* gw = (const float*)d_in[1];   // [D][E]
  const float* w1 = (const float*)d_in[2];   // [E][D][H]
  const float* b1 = (const float*)d_in[3];   // [E][H]
  const float* w2 = (const float*)d_in[4];   // [E][H][D]
  const float* b2 = (const float*)d_in[5];   // [E][D]
  float* out = (float*)d_out;

  char* p = (char*)d_ws;
  auto alloc = [&](size_t n) { char* q = p; p += (n + 255) & ~(size_t)255; return q; };
  int*   counts     = (int*)alloc(NSEG * 4);
  int*   fills      = (int*)alloc(NSEG * 4);
  int*   seg        = (int*)alloc((NSEG + 1) * 4);
  int*   tk_idx     = (int*)alloc((size_t)T_TOK * 2 * 4);
  float* tk_w       = (float*)alloc((size_t)T_TOK * 2 * 4);
  int*   row_token  = (int*)alloc((size_t)MAX_ROWS2 * 4);
  float* row_weight = (float*)alloc((size_t)MAX_ROWS2 * 4);
  int*   row_of     = (int*)alloc((size_t)T_TOK * 2 * 4);
  u16*   xc         = (u16*)alloc((size_t)T_TOK * D_DIM * 2);       // 16.8 MB bf16 x
  float* outbuf     = (float*)alloc((size_t)MAX_ROWS2 * D_DIM * 4); // 71.3 MB fp32 per-row out
  size_t meta = (size_t)(p - (char*)d_ws);

  const size_t Wfull = (size_t)E_NUM * H_DIM * D_DIM * 2;   // 67.1 MB bf16
  const size_t Wone  = (size_t)H_DIM * D_DIM * 2;           //  8.4 MB bf16
  auto hbytes = [](int n) { int cmx = (MAX_MT2 + n - 1) / n; return (size_t)cmx * BM * H_DIM * 2; };

  // mode 0: separate W1T+W2T, transposes hoisted; mode 1: shared W, transposes per chunk;
  // mode 2: per-expert W; mode 3: ws too small.
  int mode = 3, N = 1;
  {
    const int cand[6] = {1, 2, 4, 8, 16, 32};
    for (int ci = 0; ci < 6 && mode == 3; ci++)
      if (meta + 2 * Wfull + hbytes(cand[ci]) <= ws_size) { mode = 0; N = cand[ci]; }
    for (int ci = 0; ci < 6 && mode == 3; ci++)
      if (meta + Wfull + hbytes(cand[ci]) <= ws_size) { mode = 1; N = cand[ci]; }
    for (int ci = 0; ci < 6 && mode == 3; ci++)
      if (meta + Wone + hbytes(cand[ci]) <= ws_size) { mode = 2; N = cand[ci]; }
  }

  if (mode == 3) {  // ws too small for any tier: defined output, diagnostic fail
    zero4_kernel<<<(int)(((size_t)T_TOK * D_DIM) / 1024), 256, 0, stream>>>((float4*)out);
    return;
  }

  u16 *W1T, *W2T;
  if (mode == 0) { W1T = (u16*)alloc(Wfull); W2T = (u16*)alloc(Wfull); }
  else           { W1T = W2T = (u16*)alloc(mode == 1 ? Wfull : Wone); }
  u16* Hbuf = (u16*)alloc(hbytes(N));
  const int cm = (MAX_MT2 + N - 1) / N;

  init_kernel<<<(MAX_ROWS2 + 255) / 256, 256, 0, stream>>>(counts, fills, row_token);
  convert_x_kernel<<<(int)(((size_t)T_TOK * D_DIM) / 2048), 256, 0, stream>>>(x, xc);
  gate_kernel<<<T_TOK / 4, 256, 0, stream>>>(x, gw, tk_idx, tk_w, counts);
  prefix_kernel<<<1, 64, 0, stream>>>(counts, seg);
  fill_kernel<<<T_TOK / 256, 256, 0, stream>>>(tk_idx, tk_w, seg, fills, row_token, row_weight, row_of);

  if (mode == 0) {
    transpose_kernel<<<dim3(H_DIM / 64, D_DIM / 64, E_NUM), 256, 0, stream>>>(w1, W1T, D_DIM, H_DIM);
    transpose_kernel<<<dim3(D_DIM / 64, H_DIM / 64, E_NUM), 256, 0, stream>>>(w2, W2T, H_DIM, D_DIM);
  }

  for (int c = 0; c < N; ++c) {
    int mtile0 = c * cm;
    int cmc = MAX_MT2 - mtile0; if (cmc > cm) cmc = cm; if (cmc <= 0) break;
    if (mode == 0) {
      fc1_kernel<<<dim3(H_DIM / BN, cmc), 256, 0, stream>>>(xc, W1T, b1, Hbuf, row_token, seg, mtile0, -1);
      fc2_kernel<<<dim3(D_DIM / BN, cmc), 256, 0, stream>>>(Hbuf, W2T, b2, outbuf, row_token, row_weight, seg, mtile0, -1);
    } else if (mode == 1) {
      transpose_kernel<<<dim3(H_DIM / 64, D_DIM / 64, E_NUM), 256, 0, stream>>>(w1, W1T, D_DIM, H_DIM);
      fc1_kernel<<<dim3(H_DIM / BN, cmc), 256, 0, stream>>>(xc, W1T, b1, Hbuf, row_token, seg, mtile0, -1);
      transpose_kernel<<<dim3(D_DIM / 64, H_DIM / 64, E_NUM), 256, 0, stream>>>(w2, W2T, H_DIM, D_DIM);
      fc2_kernel<<<dim3(D_DIM / BN, cmc), 256, 0, stream>>>(Hbuf, W2T, b2, outbuf, row_token, row_weight, seg, mtile0, -1);
    } else {
      for (int e = 0; e < E_NUM; e++) {
        transpose_kernel<<<dim3(H_DIM / 64, D_DIM / 64, 1), 256, 0, stream>>>(w1 + (size_t)e * D_DIM * H_DIM, W1T, D_DIM, H_DIM);
        fc1_kernel<<<dim3(H_DIM / BN, cmc), 256, 0, stream>>>(xc, W1T, b1, Hbuf, row_token, seg, mtile0, e);
      }
      for (int e = 0; e < E_NUM; e++) {
        transpose_kernel<<<dim3(D_DIM / 64, H_DIM / 64, 1), 256, 0, stream>>>(w2 + (size_t)e * H_DIM * D_DIM, W2T, H_DIM, D_DIM);
        fc2_kernel<<<dim3(D_DIM / BN, cmc), 256, 0, stream>>>(Hbuf, W2T, b2, outbuf, row_token, row_weight, seg, mtile0, e);
      }
    }
  }
  combine_kernel<<<T_TOK, 256, 0, stream>>>(outbuf, row_of, out);
}